// Round 12
// baseline (253.179 us; speedup 1.0000x reference)
//
#include <hip/hip_runtime.h>

#define HD 1024
#define FD 2816
#define NE 8
#define NT 1024
#define NSLOT (NT * 2)

typedef short short8 __attribute__((ext_vector_type(8)));
typedef unsigned u32x4 __attribute__((ext_vector_type(4)));
typedef unsigned u32x2 __attribute__((ext_vector_type(2)));
typedef float f32x4 __attribute__((ext_vector_type(4)));
typedef float f32x16 __attribute__((ext_vector_type(16)));

typedef __attribute__((address_space(3))) unsigned lds_u32;
typedef __attribute__((address_space(1))) const unsigned glb_u32;

#define WAITV(N) asm volatile("s_waitcnt vmcnt(" #N ") lgkmcnt(0)" ::: "memory")
#define BARRIER() do { __builtin_amdgcn_s_barrier(); __builtin_amdgcn_sched_barrier(0); } while (0)
#define SB() __builtin_amdgcn_sched_barrier(0)

__device__ __forceinline__ void glds16(const void* g, void* l) {
  __builtin_amdgcn_global_load_lds((glb_u32*)g, (lds_u32*)l, 16, 0, 0);
}

__device__ __forceinline__ short f2bf(float f) {
  unsigned u = __builtin_bit_cast(unsigned, f);
  u += 0x7FFFu + ((u >> 16) & 1u);   // round-to-nearest-even
  return (short)(u >> 16);
}
__device__ __forceinline__ unsigned cvtpk(float lo, float hi) {
  unsigned r;
  asm("v_cvt_pk_bf16_f32 %0, %1, %2" : "=v"(r) : "v"(lo), "v"(hi));
  return r;
}
__device__ __forceinline__ int imin(int a, int b) { return a < b ? a : b; }

// ---------------- router ----------------------------------------------------
__global__ void router_kernel(const float* __restrict__ x,
                              const float* __restrict__ rw,
                              int* __restrict__ counts,
                              int* __restrict__ tok_i,
                              float* __restrict__ tok_w) {
  const int t = blockIdx.x;
  const int lane = threadIdx.x;
  const float* px = x + (size_t)t * HD;
  float acc[NE];
#pragma unroll
  for (int e = 0; e < NE; e++) acc[e] = 0.f;
  for (int h = lane; h < HD; h += 64) {
    float xv = px[h];
#pragma unroll
    for (int e = 0; e < NE; e++) acc[e] += xv * rw[e * HD + h];
  }
#pragma unroll
  for (int e = 0; e < NE; e++) {
#pragma unroll
    for (int off = 32; off > 0; off >>= 1)
      acc[e] += __shfl_xor(acc[e], off, 64);
  }
  if (lane == 0) {
    float mx = acc[0];
#pragma unroll
    for (int e = 1; e < NE; e++) mx = fmaxf(mx, acc[e]);
    float ex[NE];
#pragma unroll
    for (int e = 0; e < NE; e++) ex[e] = __expf(acc[e] - mx);
    int i1 = 0;
#pragma unroll
    for (int e = 1; e < NE; e++) if (ex[e] > ex[i1]) i1 = e;
    int i2 = (i1 == 0) ? 1 : 0;
#pragma unroll
    for (int e = 0; e < NE; e++) if (e != i1 && ex[e] > ex[i2]) i2 = e;
    float inv = 1.f / (ex[i1] + ex[i2]);
    tok_i[t * 2 + 0] = i1; tok_w[t * 2 + 0] = ex[i1] * inv;
    tok_i[t * 2 + 1] = i2; tok_w[t * 2 + 1] = ex[i2] * inv;
    atomicAdd(&counts[i1], 1);
    atomicAdd(&counts[i2], 1);
  }
}

// ---------------- scan ------------------------------------------------------
__global__ void scan_kernel(const int* __restrict__ counts,
                            int* __restrict__ bases,
                            int* __restrict__ cursor) {
  if (threadIdx.x == 0) {
    int s = 0;
    for (int e = 0; e < NE; e++) { bases[e] = s; cursor[e] = s; s += counts[e]; }
    bases[NE] = s;
  }
}

// ---------------- fill ------------------------------------------------------
__global__ void fill_kernel(const int* __restrict__ tok_i,
                            const float* __restrict__ tok_w,
                            int* __restrict__ cursor,
                            int* __restrict__ slot_token,
                            float* __restrict__ slot_w) {
  int t = blockIdx.x * 256 + threadIdx.x;
  if (t >= NT) return;
#pragma unroll
  for (int k = 0; k < 2; k++) {
    int e = tok_i[t * 2 + k];
    int pos = atomicAdd(&cursor[e], 1);
    slot_token[pos] = t;
    slot_w[pos] = tok_w[t * 2 + k];
  }
}

// ---------------- gather x -> bf16 xg (linear) ------------------------------
__global__ void gather_kernel(const float* __restrict__ x,
                              const int* __restrict__ slot_token,
                              short* __restrict__ xg) {
  const int slot = blockIdx.x;
  const int tok = slot_token[slot];
  const int t = threadIdx.x;
  f32x4 v = *(const f32x4*)(x + (size_t)tok * HD + t * 4);
  u32x2 s;
  s[0] = cvtpk(v[0], v[1]);
  s[1] = cvtpk(v[2], v[3]);
  *(u32x2*)&xg[(size_t)slot * HD + t * 4] = s;
}

// ---------------- pack W[e][K][N] fp32 -> P bf16 panels ---------------------
// P layout (shorts): [((e*KT+kt)*4 + oct)*N*8 + f*8 + j] = bf16(W[e][kt*32+oct*8+j][f])
// Reads 1KB row-runs; writes 1KB contiguous runs per wave. LDS-bounced transpose.
__global__ __launch_bounds__(256) void pack_kernel(
    const float* __restrict__ W, short* __restrict__ P, int K, int N) {
  const int f0 = blockIdx.x * 256;
  const int kt = blockIdx.y;
  const int e = blockIdx.z;
  const int KT = K / 32;
  const int k0 = kt * 32;
  __shared__ short L[32 * 264];   // [k][264 shorts], 16-byte pad per row
  const int tid = threadIdx.x;
  const int lc = tid & 63, hc = tid >> 6;
  const float* src = W + (size_t)e * K * N;

#pragma unroll
  for (int pass = 0; pass < 8; pass++) {
    int k = pass * 4 + hc;
    f32x4 v = *(const f32x4*)(src + (size_t)(k0 + k) * N + f0 + lc * 4);
    u32x2 s;
    s[0] = cvtpk(v[0], v[1]);
    s[1] = cvtpk(v[2], v[3]);
    *(u32x2*)&L[k * 264 + lc * 4] = s;
  }
  __syncthreads();
#pragma unroll
  for (int pass = 0; pass < 4; pass++) {
    int f = pass * 64 + lc;
    int oct = hc;
    unsigned w[4];
#pragma unroll
    for (int i = 0; i < 4; i++) {
      unsigned lo = (unsigned short)L[(oct * 8 + 2 * i) * 264 + f];
      unsigned hi = (unsigned short)L[(oct * 8 + 2 * i + 1) * 264 + f];
      w[i] = lo | (hi << 16);
    }
    size_t off = ((size_t)((e * KT + kt) * 4 + oct)) * N * 8 + (size_t)(f0 + f) * 8;
    *(u32x4*)&P[off] = *(u32x4*)w;
  }
}

// ============ gate/up grouped GEMM (BM=128 BN=64 BK=32, all-glds 3-deep) ====
// grid: (352, 16): x = e*44+nt, y = mt. block 256 (4 waves 2m x 2n)

#define G_STAGE(S, T) do {                                           \
    glds16(asrc0 + (T) * 32, &As[S][wid * 512]);                     \
    glds16(asrc1 + (T) * 32, &As[S][2048 + wid * 512]);              \
    glds16(bsrc + (size_t)(T) * 90112, &Bs[S][wid * 512]);           \
  } while (0)

#define G_COMPUTE(S) do {                                                     \
    _Pragma("unroll")                                                         \
    for (int ks = 0; ks < 2; ks++) {                                          \
      const int oct = ks * 2 + l5;                                            \
      short8 a0, a1, b;                                                       \
      { int r = wm * 64 + l31, p = r >> 1;                                    \
        a0 = *(const short8*)&As[S][p * 64 +                                  \
              ((((r & 1) << 2) | oct) ^ (p & 7)) * 8]; }                      \
      { int r = wm * 64 + 32 + l31, p = r >> 1;                               \
        a1 = *(const short8*)&As[S][p * 64 +                                  \
              ((((r & 1) << 2) | oct) ^ (p & 7)) * 8]; }                      \
      { int n = wn * 32 + l31, pn = n >> 1;                                   \
        b = *(const short8*)&Bs[S][pn * 64 +                                  \
              ((((n & 1) << 2) | oct) ^ (pn & 7)) * 8]; }                     \
      acc0 = __builtin_amdgcn_mfma_f32_32x32x16_bf16(a0, b, acc0, 0, 0, 0);   \
      acc1 = __builtin_amdgcn_mfma_f32_32x32x16_bf16(a1, b, acc1, 0, 0, 0);   \
    }                                                                         \
  } while (0)

#define G_ITER(S, T) do {    \
    G_COMPUTE(S);            \
    BARRIER();               \
    G_STAGE(S, (T) + 3);     \
    WAITV(6);                \
    BARRIER();               \
  } while (0)

__global__ __launch_bounds__(256, 4) void gemm_gu_kernel(
    const short* __restrict__ xg, const short* __restrict__ P,
    const int* __restrict__ bases, short* __restrict__ m_out) {
  const int bx = blockIdx.x;
  const int e = bx / 44, nt = bx - e * 44;
  const int b0 = bases[e];
  const int ne = bases[e + 1] - b0;
  const int row0 = blockIdx.y * 128;
  if (row0 >= ne) return;
  const int n0 = nt * 64;

  __shared__ short As[3][4096];   // 128 rows x 32 k, pair-line
  __shared__ short Bs[3][2048];   // 64 n-rows x 32 k, pair-line

  const int tid = threadIdx.x;
  const int lane = tid & 63, wid = tid >> 6;
  const int l31 = lane & 31, l5 = lane >> 5;
  const int wm = wid >> 1, wn = wid & 1;

  const short *asrc0, *asrc1;
  {
    int i = tid;
    int p = i >> 3, j = i & 7, v = j ^ (p & 7);
    int r = 2 * p + (v >> 2), c = v & 3;
    asrc0 = xg + (size_t)(b0 + imin(row0 + r, ne - 1)) * HD + c * 8;
    i = 256 + tid;
    p = i >> 3; j = i & 7; v = j ^ (p & 7);
    r = 2 * p + (v >> 2); c = v & 3;
    asrc1 = xg + (size_t)(b0 + imin(row0 + r, ne - 1)) * HD + c * 8;
  }
  const short* bsrc;
  {
    int p = tid >> 3, j = tid & 7, v = j ^ (p & 7);
    int r = 2 * p + (v >> 2), c = v & 3;
    // KT=32, N=FD: base of kt=0, octet c, row n0+r
    bsrc = P + ((size_t)(e * 32 * 4 + c)) * (FD * 8) + (size_t)(n0 + r) * 8;
  }

  f32x16 acc0 = (f32x16)0.f, acc1 = (f32x16)0.f;

  G_STAGE(0, 0); G_STAGE(1, 1); G_STAGE(2, 2);
  WAITV(6);
  BARRIER();

  for (int t = 0; t < 27; t += 3) {
    G_ITER(0, t);
    G_ITER(1, t + 1);
    G_ITER(2, t + 2);
  }
  G_ITER(0, 27);
  G_ITER(1, 28);
  G_COMPUTE(2);            // t=29
  WAITV(3); BARRIER();
  G_COMPUTE(0);            // t=30
  WAITV(0); BARRIER();
  G_COMPUTE(1);            // t=31

#pragma unroll
  for (int q = 0; q < 16; q++) {
    int rb_ = (q & 3) + 8 * (q >> 2) + 4 * l5;
    {
      int r = row0 + wm * 64 + rb_;
      if (r < ne)
        m_out[(size_t)(b0 + r) * FD + n0 + wn * 32 + l31] = f2bf(acc0[q]);
    }
    {
      int r = row0 + wm * 64 + 32 + rb_;
      if (r < ne)
        m_out[(size_t)(b0 + r) * FD + n0 + wn * 32 + l31] = f2bf(acc1[q]);
    }
  }
}

// ---------------- silu(g)*u elementwise, in-place into mg -------------------
__global__ void silu_kernel(short* __restrict__ mg, const short* __restrict__ mu) {
  size_t id = (size_t)blockIdx.x * 256 + threadIdx.x;   // 720896 short8 chunks
  short8 g8 = *(const short8*)&mg[id * 8];
  short8 u8 = *(const short8*)&mu[id * 8];
  short8 o;
#pragma unroll
  for (int j = 0; j < 8; j++) {
    float g = __builtin_bit_cast(float, (unsigned)((unsigned short)g8[j]) << 16);
    float u = __builtin_bit_cast(float, (unsigned)((unsigned short)u8[j]) << 16);
    o[j] = f2bf((g / (1.f + __expf(-g))) * u);
  }
  *(short8*)&mg[id * 8] = o;
}

// ============ down grouped GEMM (BM=64 BN=64 BK=32, all-glds 3-deep) ========
// grid: (128, 32): x = e*16+nt, y = mt. block 256 (4 waves 2m x 2n)

#define D_STAGE(S, T) do {                                           \
    glds16(asrc + (T) * 32, &As[S][wid * 512]);                      \
    glds16(bsrc + (size_t)(T) * 32768, &Bs[S][wid * 512]);           \
  } while (0)

#define D_COMPUTE(S) do {                                                     \
    _Pragma("unroll")                                                         \
    for (int ks = 0; ks < 2; ks++) {                                          \
      const int oct = ks * 2 + l5;                                            \
      short8 a, b;                                                            \
      { int r = wm * 32 + l31, p = r >> 1;                                    \
        a = *(const short8*)&As[S][p * 64 +                                   \
              ((((r & 1) << 2) | oct) ^ (p & 7)) * 8]; }                      \
      { int n = wn * 32 + l31, pn = n >> 1;                                   \
        b = *(const short8*)&Bs[S][pn * 64 +                                  \
              ((((n & 1) << 2) | oct) ^ (pn & 7)) * 8]; }                     \
      acc = __builtin_amdgcn_mfma_f32_32x32x16_bf16(a, b, acc, 0, 0, 0);      \
    }                                                                         \
  } while (0)

#define D_ITER(S, T) do {    \
    D_COMPUTE(S);            \
    BARRIER();               \
    D_STAGE(S, (T) + 3);     \
    WAITV(4);                \
    BARRIER();               \
  } while (0)

__global__ __launch_bounds__(256, 4) void down_kernel(
    const short* __restrict__ m_in, const short* __restrict__ P,
    const int* __restrict__ bases, const float* __restrict__ slot_w,
    const int* __restrict__ slot_token, float* __restrict__ out) {
  const int bx = blockIdx.x;
  const int e = bx >> 4, nt = bx & 15;
  const int b0 = bases[e];
  const int ne = bases[e + 1] - b0;
  const int row0 = blockIdx.y * 64;
  if (row0 >= ne) return;
  const int n0 = nt * 64;

  __shared__ short As[3][2048];
  __shared__ short Bs[3][2048];

  const int tid = threadIdx.x;
  const int lane = tid & 63, wid = tid >> 6;
  const int l31 = lane & 31, l5 = lane >> 5;
  const int wm = wid >> 1, wn = wid & 1;

  const short* asrc;
  {
    int p = tid >> 3, j = tid & 7, v = j ^ (p & 7);
    int r = 2 * p + (v >> 2), c = v & 3;
    asrc = m_in + (size_t)(b0 + imin(row0 + r, ne - 1)) * FD + c * 8;
  }
  const short* bsrc;
  {
    int p = tid >> 3, j = tid & 7, v = j ^ (p & 7);
    int r = 2 * p + (v >> 2), c = v & 3;
    // KT=88, N=HD
    bsrc = P + ((size_t)(e * 88 * 4 + c)) * (HD * 8) + (size_t)(n0 + r) * 8;
  }

  f32x16 acc = (f32x16)0.f;

  D_STAGE(0, 0); D_STAGE(1, 1); D_STAGE(2, 2);
  WAITV(4);
  BARRIER();

  for (int t = 0; t < 84; t += 3) {   // NTL = 88
    D_ITER(0, t);
    D_ITER(1, t + 1);
    D_ITER(2, t + 2);
  }
  D_ITER(0, 84);
  D_COMPUTE(1);            // t=85
  WAITV(2); BARRIER();
  D_COMPUTE(2);            // t=86
  WAITV(0); BARRIER();
  D_COMPUTE(0);            // t=87

#pragma unroll
  for (int q = 0; q < 16; q++) {
    int r = row0 + wm * 32 + (q & 3) + 8 * (q >> 2) + 4 * l5;
    if (r < ne) {
      int slot = b0 + r;
      int tok = slot_token[slot];
      atomicAdd(&out[(size_t)tok * HD + n0 + wn * 32 + l31],
                acc[q] * slot_w[slot]);
    }
  }
}

extern "C" void kernel_launch(void* const* d_in, const int* in_sizes, int n_in,
                              void* d_out, int out_size, void* d_ws,
                              size_t ws_size, hipStream_t stream) {
  const float* x = (const float*)d_in[0];
  const float* rw = (const float*)d_in[1];
  const float* gw = (const float*)d_in[2];
  const float* uw = (const float*)d_in[3];
  const float* dw = (const float*)d_in[4];
  float* out = (float*)d_out;

  char* ws = (char*)d_ws;
  int* counts = (int*)(ws + 0);
  int* cursor = (int*)(ws + 64);
  int* bases = (int*)(ws + 128);
  int* tok_i = (int*)(ws + 256);
  float* tok_w = (float*)(ws + 8448);
  int* slot_token = (int*)(ws + 16640);
  float* slot_w = (float*)(ws + 24832);
  short* xg = (short*)(ws + 41216);         // 2048 x 1024 bf16       (4.19 MB)
  short* mg = (short*)(ws + 4235520);       // 2048 x 2816 bf16       (11.5 MB)
  short* mu = (short*)(ws + 15769856);      // 2048 x 2816 bf16       (11.5 MB)
  short* P  = (short*)(ws + 27304192);      // packed panels          (46.1 MB)

  (void)hipMemsetAsync(counts, 0, 64, stream);
  (void)hipMemsetAsync(out, 0, (size_t)out_size * 4, stream);
  router_kernel<<<NT, 64, 0, stream>>>(x, rw, counts, tok_i, tok_w);
  scan_kernel<<<1, 64, 0, stream>>>(counts, bases, cursor);
  fill_kernel<<<NT / 256, 256, 0, stream>>>(tok_i, tok_w, cursor, slot_token,
                                            slot_w);
  gather_kernel<<<NSLOT, 256, 0, stream>>>(x, slot_token, xg);

  // gate: pack -> GEMM -> mg
  pack_kernel<<<dim3(11, 32, NE), 256, 0, stream>>>(gw, P, HD, FD);
  gemm_gu_kernel<<<dim3(352, 16), 256, 0, stream>>>(xg, P, bases, mg);
  // up: pack (reuse P) -> GEMM -> mu
  pack_kernel<<<dim3(11, 32, NE), 256, 0, stream>>>(uw, P, HD, FD);
  gemm_gu_kernel<<<dim3(352, 16), 256, 0, stream>>>(xg, P, bases, mu);
  // m = silu(mg)*mu  (in place into mg)
  silu_kernel<<<2816, 256, 0, stream>>>(mg, mu);
  // down: pack (reuse P) -> GEMM -> atomic combine into out
  pack_kernel<<<dim3(4, 88, NE), 256, 0, stream>>>(dw, P, FD, HD);
  down_kernel<<<dim3(128, 32), 256, 0, stream>>>(mg, P, bases, slot_w,
                                                 slot_token, out);
}

// Round 13
// 250.123 us; speedup vs baseline: 1.0122x; 1.0122x over previous
//
#include <hip/hip_runtime.h>

#define HD 1024
#define FD 2816
#define NE 8
#define NT 1024
#define NSLOT (NT * 2)

typedef short short8 __attribute__((ext_vector_type(8)));
typedef unsigned u32x4 __attribute__((ext_vector_type(4)));
typedef unsigned u32x2 __attribute__((ext_vector_type(2)));
typedef float f32x4 __attribute__((ext_vector_type(4)));
typedef float f32x16 __attribute__((ext_vector_type(16)));

typedef __attribute__((address_space(3))) unsigned lds_u32;
typedef __attribute__((address_space(1))) const unsigned glb_u32;

#define WAITV(N) asm volatile("s_waitcnt vmcnt(" #N ") lgkmcnt(0)" ::: "memory")
#define BARRIER() do { __builtin_amdgcn_s_barrier(); __builtin_amdgcn_sched_barrier(0); } while (0)
#define SB() __builtin_amdgcn_sched_barrier(0)

__device__ __forceinline__ void glds16(const void* g, void* l) {
  __builtin_amdgcn_global_load_lds((glb_u32*)g, (lds_u32*)l, 16, 0, 0);
}

__device__ __forceinline__ short f2bf(float f) {
  unsigned u = __builtin_bit_cast(unsigned, f);
  u += 0x7FFFu + ((u >> 16) & 1u);   // round-to-nearest-even
  return (short)(u >> 16);
}
__device__ __forceinline__ unsigned cvtpk(float lo, float hi) {
  unsigned r;
  asm("v_cvt_pk_bf16_f32 %0, %1, %2" : "=v"(r) : "v"(lo), "v"(hi));
  return r;
}
__device__ __forceinline__ int imin(int a, int b) { return a < b ? a : b; }

// ---------------- router ----------------------------------------------------
__global__ void router_kernel(const float* __restrict__ x,
                              const float* __restrict__ rw,
                              int* __restrict__ counts,
                              int* __restrict__ tok_i,
                              float* __restrict__ tok_w) {
  const int t = blockIdx.x;
  const int lane = threadIdx.x;
  const float* px = x + (size_t)t * HD;
  float acc[NE];
#pragma unroll
  for (int e = 0; e < NE; e++) acc[e] = 0.f;
  for (int h = lane; h < HD; h += 64) {
    float xv = px[h];
#pragma unroll
    for (int e = 0; e < NE; e++) acc[e] += xv * rw[e * HD + h];
  }
#pragma unroll
  for (int e = 0; e < NE; e++) {
#pragma unroll
    for (int off = 32; off > 0; off >>= 1)
      acc[e] += __shfl_xor(acc[e], off, 64);
  }
  if (lane == 0) {
    float mx = acc[0];
#pragma unroll
    for (int e = 1; e < NE; e++) mx = fmaxf(mx, acc[e]);
    float ex[NE];
#pragma unroll
    for (int e = 0; e < NE; e++) ex[e] = __expf(acc[e] - mx);
    int i1 = 0;
#pragma unroll
    for (int e = 1; e < NE; e++) if (ex[e] > ex[i1]) i1 = e;
    int i2 = (i1 == 0) ? 1 : 0;
#pragma unroll
    for (int e = 0; e < NE; e++) if (e != i1 && ex[e] > ex[i2]) i2 = e;
    float inv = 1.f / (ex[i1] + ex[i2]);
    tok_i[t * 2 + 0] = i1; tok_w[t * 2 + 0] = ex[i1] * inv;
    tok_i[t * 2 + 1] = i2; tok_w[t * 2 + 1] = ex[i2] * inv;
    atomicAdd(&counts[i1], 1);
    atomicAdd(&counts[i2], 1);
  }
}

// ---------------- scan ------------------------------------------------------
__global__ void scan_kernel(const int* __restrict__ counts,
                            int* __restrict__ bases,
                            int* __restrict__ cursor) {
  if (threadIdx.x == 0) {
    int s = 0;
    for (int e = 0; e < NE; e++) { bases[e] = s; cursor[e] = s; s += counts[e]; }
    bases[NE] = s;
  }
}

// ---------------- fill ------------------------------------------------------
__global__ void fill_kernel(const int* __restrict__ tok_i,
                            const float* __restrict__ tok_w,
                            int* __restrict__ cursor,
                            int* __restrict__ slot_token,
                            float* __restrict__ slot_w) {
  int t = blockIdx.x * 256 + threadIdx.x;
  if (t >= NT) return;
#pragma unroll
  for (int k = 0; k < 2; k++) {
    int e = tok_i[t * 2 + k];
    int pos = atomicAdd(&cursor[e], 1);
    slot_token[pos] = t;
    slot_w[pos] = tok_w[t * 2 + k];
  }
}

// ---------------- gather x -> bf16 xg (linear) ------------------------------
__global__ void gather_kernel(const float* __restrict__ x,
                              const int* __restrict__ slot_token,
                              short* __restrict__ xg) {
  const int slot = blockIdx.x;
  const int tok = slot_token[slot];
  const int t = threadIdx.x;
  f32x4 v = *(const f32x4*)(x + (size_t)tok * HD + t * 4);
  u32x2 s;
  s[0] = cvtpk(v[0], v[1]);
  s[1] = cvtpk(v[2], v[3]);
  *(u32x2*)&xg[(size_t)slot * HD + t * 4] = s;
}

// ---------------- pack v2: W[e][K][N] fp32 -> bf16 panels, no LDS ----------
// P chunk [((e*KT+kt)*4+oct)*N + f] (16B) = bf16(W[e][kt*32+oct*8 + 0..7][f])
// Wave reads 8 x 1KB-coalesced k-rows; in-lane cvtpk; L2-merged 16B stores.
__global__ __launch_bounds__(256) void pack_kernel(
    const float* __restrict__ W0, const float* __restrict__ W1,
    short* __restrict__ P0, short* __restrict__ P1, int K, int N, int EH) {
  const int f0 = blockIdx.x * 256;
  const int kt = blockIdx.y;
  int ez = blockIdx.z;
  const float* W = W0; short* P = P0;
  if (ez >= EH) { W = W1; P = P1; ez -= EH; }
  const int KT = K / 32;
  const int lane = threadIdx.x & 63, w = threadIdx.x >> 6;
  const float* src = W + (size_t)ez * K * N + (size_t)(kt * 32 + w * 8) * N +
                     f0 + lane * 4;
  f32x4 x0 = *(const f32x4*)(src);
  f32x4 x1 = *(const f32x4*)(src + (size_t)N);
  f32x4 x2 = *(const f32x4*)(src + (size_t)2 * N);
  f32x4 x3 = *(const f32x4*)(src + (size_t)3 * N);
  f32x4 x4 = *(const f32x4*)(src + (size_t)4 * N);
  f32x4 x5 = *(const f32x4*)(src + (size_t)5 * N);
  f32x4 x6 = *(const f32x4*)(src + (size_t)6 * N);
  f32x4 x7 = *(const f32x4*)(src + (size_t)7 * N);
  short* dst = P + (((size_t)(ez * KT + kt) * 4 + w) * N + f0 + lane * 4) * 8;
#pragma unroll
  for (int j = 0; j < 4; j++) {
    u32x4 c;
    c[0] = cvtpk(x0[j], x1[j]);
    c[1] = cvtpk(x2[j], x3[j]);
    c[2] = cvtpk(x4[j], x5[j]);
    c[3] = cvtpk(x6[j], x7[j]);
    *(u32x4*)(dst + (size_t)j * 8) = c;
  }
}

// ============ fused gate+up GEMM (BM=128 BN=64x2 BK=32, all-glds 3-deep) ====
// grid: (352, 16): x = e*44+nt, y = mt. block 256 (4 waves 2m x 2n)

#define G_STAGE(S, T) do {                                           \
    glds16(asrc0 + (T) * 32, &As[S][wid * 512]);                     \
    glds16(asrc1 + (T) * 32, &As[S][2048 + wid * 512]);              \
    glds16(bgsrc + (size_t)(T) * 90112, &Bg[S][wid * 512]);          \
    glds16(busrc + (size_t)(T) * 90112, &Bu[S][wid * 512]);          \
  } while (0)

#define G_COMPUTE(S) do {                                                     \
    _Pragma("unroll")                                                         \
    for (int ks = 0; ks < 2; ks++) {                                          \
      const int oct = ks * 2 + l5;                                            \
      short8 a0, a1, bg, bu;                                                  \
      { int r = wm * 64 + l31, p = r >> 1;                                    \
        a0 = *(const short8*)&As[S][p * 64 +                                  \
              ((((r & 1) << 2) | oct) ^ (p & 7)) * 8]; }                      \
      { int r = wm * 64 + 32 + l31, p = r >> 1;                               \
        a1 = *(const short8*)&As[S][p * 64 +                                  \
              ((((r & 1) << 2) | oct) ^ (p & 7)) * 8]; }                      \
      { int n = wn * 32 + l31, pn = n >> 1;                                   \
        int off = pn * 64 + ((((n & 1) << 2) | oct) ^ (pn & 7)) * 8;          \
        bg = *(const short8*)&Bg[S][off];                                     \
        bu = *(const short8*)&Bu[S][off]; }                                   \
      accG0 = __builtin_amdgcn_mfma_f32_32x32x16_bf16(a0, bg, accG0, 0, 0, 0);\
      accU0 = __builtin_amdgcn_mfma_f32_32x32x16_bf16(a0, bu, accU0, 0, 0, 0);\
      accG1 = __builtin_amdgcn_mfma_f32_32x32x16_bf16(a1, bg, accG1, 0, 0, 0);\
      accU1 = __builtin_amdgcn_mfma_f32_32x32x16_bf16(a1, bu, accU1, 0, 0, 0);\
    }                                                                         \
  } while (0)

#define G_ITER(S, T) do {    \
    G_COMPUTE(S);            \
    BARRIER();               \
    G_STAGE(S, (T) + 3);     \
    WAITV(8);                \
    BARRIER();               \
  } while (0)

__global__ __launch_bounds__(256, 3) void gemm_gu_kernel(
    const short* __restrict__ xg, const short* __restrict__ Pg,
    const short* __restrict__ Pu, const int* __restrict__ bases,
    short* __restrict__ m_out) {
  const int bx = blockIdx.x;
  const int e = bx / 44, nt = bx - e * 44;
  const int b0 = bases[e];
  const int ne = bases[e + 1] - b0;
  const int row0 = blockIdx.y * 128;
  if (row0 >= ne) return;
  const int n0 = nt * 64;

  __shared__ short As[3][4096];   // 128 rows x 32 k, pair-line
  __shared__ short Bg[3][2048];   // 64 n x 32 k, pair-line
  __shared__ short Bu[3][2048];

  const int tid = threadIdx.x;
  const int lane = tid & 63, wid = tid >> 6;
  const int l31 = lane & 31, l5 = lane >> 5;
  const int wm = wid >> 1, wn = wid & 1;

  const short *asrc0, *asrc1;
  {
    int i = tid;
    int p = i >> 3, j = i & 7, v = j ^ (p & 7);
    int r = 2 * p + (v >> 2), c = v & 3;
    asrc0 = xg + (size_t)(b0 + imin(row0 + r, ne - 1)) * HD + c * 8;
    i = 256 + tid;
    p = i >> 3; j = i & 7; v = j ^ (p & 7);
    r = 2 * p + (v >> 2); c = v & 3;
    asrc1 = xg + (size_t)(b0 + imin(row0 + r, ne - 1)) * HD + c * 8;
  }
  const short *bgsrc, *busrc;
  {
    int p = tid >> 3, j = tid & 7, v = j ^ (p & 7);
    int r = 2 * p + (v >> 2), c = v & 3;
    size_t off = ((size_t)(e * 32 * 4 + c)) * (FD * 8) + (size_t)(n0 + r) * 8;
    bgsrc = Pg + off;
    busrc = Pu + off;
  }

  f32x16 accG0 = (f32x16)0.f, accG1 = (f32x16)0.f;
  f32x16 accU0 = (f32x16)0.f, accU1 = (f32x16)0.f;

  G_STAGE(0, 0); G_STAGE(1, 1); G_STAGE(2, 2);
  WAITV(8);
  BARRIER();

  for (int t = 0; t < 27; t += 3) {   // NTL = 32
    G_ITER(0, t);
    G_ITER(1, t + 1);
    G_ITER(2, t + 2);
  }
  G_ITER(0, 27);
  G_ITER(1, 28);
  G_COMPUTE(2);            // t=29
  WAITV(4); BARRIER();
  G_COMPUTE(0);            // t=30
  WAITV(0); BARRIER();
  G_COMPUTE(1);            // t=31

#pragma unroll
  for (int q = 0; q < 16; q++) {
    int rb_ = (q & 3) + 8 * (q >> 2) + 4 * l5;
    {
      int r = row0 + wm * 64 + rb_;
      if (r < ne) {
        float g = accG0[q], u = accU0[q];
        float mv = (g / (1.f + __expf(-g))) * u;
        m_out[(size_t)(b0 + r) * FD + n0 + wn * 32 + l31] = f2bf(mv);
      }
    }
    {
      int r = row0 + wm * 64 + 32 + rb_;
      if (r < ne) {
        float g = accG1[q], u = accU1[q];
        float mv = (g / (1.f + __expf(-g))) * u;
        m_out[(size_t)(b0 + r) * FD + n0 + wn * 32 + l31] = f2bf(mv);
      }
    }
  }
}

// ============ down grouped GEMM (BM=64 BN=64 BK=64, all-glds 3-deep) ========
// grid: (128, 32): x = e*16+nt, y = mt. block 256 (4 waves 2m x 2n)

#define D_STAGE(S, T) do {                                           \
    glds16(asrcA0 + (T) * 64, &As[S][wid * 512]);                    \
    glds16(asrcA1 + (T) * 64, &As[S][2048 + wid * 512]);             \
    glds16(bsrc0 + (size_t)(T) * 65536, &Bs[S][wid * 512]);          \
    glds16(bsrc1 + (size_t)(T) * 65536, &Bs[S][2048 + wid * 512]);   \
  } while (0)

#define D_COMPUTE(S) do {                                                     \
    _Pragma("unroll")                                                         \
    for (int ks = 0; ks < 4; ks++) {                                          \
      const int sub = ks >> 1, oct = (ks & 1) * 2 + l5;                       \
      short8 a, b;                                                            \
      { int r = wm * 32 + l31, p = r >> 1;                                    \
        a = *(const short8*)&As[S][sub * 2048 + p * 64 +                      \
              ((((r & 1) << 2) | oct) ^ (p & 7)) * 8]; }                      \
      { int n = wn * 32 + l31, pn = n >> 1;                                   \
        b = *(const short8*)&Bs[S][sub * 2048 + pn * 64 +                     \
              ((((n & 1) << 2) | oct) ^ (pn & 7)) * 8]; }                     \
      acc = __builtin_amdgcn_mfma_f32_32x32x16_bf16(a, b, acc, 0, 0, 0);      \
    }                                                                         \
  } while (0)

#define D_ITER(S, T) do {    \
    D_COMPUTE(S);            \
    BARRIER();               \
    D_STAGE(S, (T) + 3);     \
    WAITV(8);                \
    BARRIER();               \
  } while (0)

__global__ __launch_bounds__(256, 3) void down_kernel(
    const short* __restrict__ m_in, const short* __restrict__ Pd,
    const int* __restrict__ bases, const float* __restrict__ slot_w,
    const int* __restrict__ slot_token, float* __restrict__ out) {
  const int bx = blockIdx.x;
  const int e = bx >> 4, nt = bx & 15;
  const int b0 = bases[e];
  const int ne = bases[e + 1] - b0;
  const int row0 = blockIdx.y * 64;
  if (row0 >= ne) return;
  const int n0 = nt * 64;

  __shared__ short As[3][4096];   // [sub(2)][64 rows x 32 k pair-line]
  __shared__ short Bs[3][4096];   // [ktq(2)][64 n x 32 k pair-line]

  const int tid = threadIdx.x;
  const int lane = tid & 63, wid = tid >> 6;
  const int l31 = lane & 31, l5 = lane >> 5;
  const int wm = wid >> 1, wn = wid & 1;

  const short *asrcA0, *asrcA1;
  {
    int p = tid >> 3, j = tid & 7, v = j ^ (p & 7);
    int r = 2 * p + (v >> 2), c = v & 3;
    const short* base = m_in + (size_t)(b0 + imin(row0 + r, ne - 1)) * FD;
    asrcA0 = base + c * 8;          // sub 0: k 0..31
    asrcA1 = base + 32 + c * 8;     // sub 1: k 32..63
  }
  const short *bsrc0, *bsrc1;
  {
    int p = tid >> 3, j = tid & 7, v = j ^ (p & 7);
    int r = 2 * p + (v >> 2), c = v & 3;
    bsrc0 = Pd + ((size_t)((e * 88 + 0) * 4 + c)) * (HD * 8) + (size_t)(n0 + r) * 8;
    bsrc1 = Pd + ((size_t)((e * 88 + 1) * 4 + c)) * (HD * 8) + (size_t)(n0 + r) * 8;
  }

  f32x16 acc = (f32x16)0.f;

  D_STAGE(0, 0); D_STAGE(1, 1); D_STAGE(2, 2);
  WAITV(8);
  BARRIER();

  for (int t = 0; t < 39; t += 3) {   // NTL = 44: tiles 0..38
    D_ITER(0, t);
    D_ITER(1, t + 1);
    D_ITER(2, t + 2);
  }
  D_ITER(0, 39);
  D_ITER(1, 40);
  D_COMPUTE(2);            // t=41
  WAITV(4); BARRIER();
  D_COMPUTE(0);            // t=42
  WAITV(0); BARRIER();
  D_COMPUTE(1);            // t=43

#pragma unroll
  for (int q = 0; q < 16; q++) {
    int r = row0 + wm * 32 + (q & 3) + 8 * (q >> 2) + 4 * l5;
    if (r < ne) {
      int slot = b0 + r;
      int tok = slot_token[slot];
      atomicAdd(&out[(size_t)tok * HD + n0 + wn * 32 + l31],
                acc[q] * slot_w[slot]);
    }
  }
}

extern "C" void kernel_launch(void* const* d_in, const int* in_sizes, int n_in,
                              void* d_out, int out_size, void* d_ws,
                              size_t ws_size, hipStream_t stream) {
  const float* x = (const float*)d_in[0];
  const float* rw = (const float*)d_in[1];
  const float* gw = (const float*)d_in[2];
  const float* uw = (const float*)d_in[3];
  const float* dw = (const float*)d_in[4];
  float* out = (float*)d_out;

  char* ws = (char*)d_ws;
  int* counts = (int*)(ws + 0);
  int* cursor = (int*)(ws + 64);
  int* bases = (int*)(ws + 128);
  int* tok_i = (int*)(ws + 256);
  float* tok_w = (float*)(ws + 8448);
  int* slot_token = (int*)(ws + 16640);
  float* slot_w = (float*)(ws + 24832);
  short* xg = (short*)(ws + 41216);         // 2048 x 1024 bf16      (4.19 MB)
  short* m  = (short*)(ws + 4235520);       // 2048 x 2816 bf16      (11.5 MB)
  short* Pg = (short*)(ws + 15769856);      // gate panels           (46.1 MB)
  short* Pu = (short*)(ws + 61907200);      // up panels             (46.1 MB)
  short* Pd = Pg;                            // down panels alias gate (dead)

  (void)hipMemsetAsync(counts, 0, 64, stream);
  (void)hipMemsetAsync(out, 0, (size_t)out_size * 4, stream);
  router_kernel<<<NT, 64, 0, stream>>>(x, rw, counts, tok_i, tok_w);
  scan_kernel<<<1, 64, 0, stream>>>(counts, bases, cursor);
  fill_kernel<<<NT / 256, 256, 0, stream>>>(tok_i, tok_w, cursor, slot_token,
                                            slot_w);
  gather_kernel<<<NSLOT, 256, 0, stream>>>(x, slot_token, xg);

  // pack gate+up (one launch) -> fused gate/up GEMM with silu epilogue -> m
  pack_kernel<<<dim3(FD / 256, 32, 16), 256, 0, stream>>>(gw, uw, Pg, Pu,
                                                          HD, FD, NE);
  gemm_gu_kernel<<<dim3(352, 16), 256, 0, stream>>>(xg, Pg, Pu, bases, m);
  // pack down (reuses Pg region) -> down GEMM -> atomic combine into out
  pack_kernel<<<dim3(HD / 256, 88, 8), 256, 0, stream>>>(dw, dw, Pd, Pd,
                                                         FD, HD, NE);
  down_kernel<<<dim3(128, 32), 256, 0, stream>>>(m, Pd, bases, slot_w,
                                                 slot_token, out);
}

// Round 14
// 198.776 us; speedup vs baseline: 1.2737x; 1.2583x over previous
//
#include <hip/hip_runtime.h>

#define HD 1024
#define FD 2816
#define NE 8
#define NT 1024
#define NSLOT (NT * 2)

typedef short short8 __attribute__((ext_vector_type(8)));
typedef unsigned u32x4 __attribute__((ext_vector_type(4)));
typedef unsigned u32x2 __attribute__((ext_vector_type(2)));
typedef float f32x4 __attribute__((ext_vector_type(4)));
typedef float f32x16 __attribute__((ext_vector_type(16)));

typedef __attribute__((address_space(3))) unsigned lds_u32;
typedef __attribute__((address_space(1))) const unsigned glb_u32;

#define WAITV(N) asm volatile("s_waitcnt vmcnt(" #N ") lgkmcnt(0)" ::: "memory")
#define BARRIER() do { __builtin_amdgcn_s_barrier(); __builtin_amdgcn_sched_barrier(0); } while (0)
#define SB() __builtin_amdgcn_sched_barrier(0)

__device__ __forceinline__ void glds16(const void* g, void* l) {
  __builtin_amdgcn_global_load_lds((glb_u32*)g, (lds_u32*)l, 16, 0, 0);
}

__device__ __forceinline__ short f2bf(float f) {
  unsigned u = __builtin_bit_cast(unsigned, f);
  u += 0x7FFFu + ((u >> 16) & 1u);   // round-to-nearest-even
  return (short)(u >> 16);
}
__device__ __forceinline__ unsigned cvtpk(float lo, float hi) {
  unsigned r;
  asm("v_cvt_pk_bf16_f32 %0, %1, %2" : "=v"(r) : "v"(lo), "v"(hi));
  return r;
}
__device__ __forceinline__ int imin(int a, int b) { return a < b ? a : b; }

// ---------------- router ----------------------------------------------------
__global__ void router_kernel(const float* __restrict__ x,
                              const float* __restrict__ rw,
                              int* __restrict__ counts,
                              int* __restrict__ tok_i,
                              float* __restrict__ tok_w) {
  const int t = blockIdx.x;
  const int lane = threadIdx.x;
  const float* px = x + (size_t)t * HD;
  float acc[NE];
#pragma unroll
  for (int e = 0; e < NE; e++) acc[e] = 0.f;
  for (int h = lane; h < HD; h += 64) {
    float xv = px[h];
#pragma unroll
    for (int e = 0; e < NE; e++) acc[e] += xv * rw[e * HD + h];
  }
#pragma unroll
  for (int e = 0; e < NE; e++) {
#pragma unroll
    for (int off = 32; off > 0; off >>= 1)
      acc[e] += __shfl_xor(acc[e], off, 64);
  }
  if (lane == 0) {
    float mx = acc[0];
#pragma unroll
    for (int e = 1; e < NE; e++) mx = fmaxf(mx, acc[e]);
    float ex[NE];
#pragma unroll
    for (int e = 0; e < NE; e++) ex[e] = __expf(acc[e] - mx);
    int i1 = 0;
#pragma unroll
    for (int e = 1; e < NE; e++) if (ex[e] > ex[i1]) i1 = e;
    int i2 = (i1 == 0) ? 1 : 0;
#pragma unroll
    for (int e = 0; e < NE; e++) if (e != i1 && ex[e] > ex[i2]) i2 = e;
    float inv = 1.f / (ex[i1] + ex[i2]);
    tok_i[t * 2 + 0] = i1; tok_w[t * 2 + 0] = ex[i1] * inv;
    tok_i[t * 2 + 1] = i2; tok_w[t * 2 + 1] = ex[i2] * inv;
    atomicAdd(&counts[i1], 1);
    atomicAdd(&counts[i2], 1);
  }
}

// ---------------- fused scan+fill (one block) -------------------------------
__global__ void scanfill_kernel(const int* __restrict__ counts,
                                const int* __restrict__ tok_i,
                                const float* __restrict__ tok_w,
                                int* __restrict__ bases,
                                int* __restrict__ slot_token,
                                float* __restrict__ slot_w) {
  __shared__ int cur[NE];
  const int t = threadIdx.x;   // 1024 threads, 1 token each
  if (t == 0) {
    int s = 0;
    for (int e = 0; e < NE; e++) { bases[e] = s; cur[e] = s; s += counts[e]; }
    bases[NE] = s;
  }
  __syncthreads();
#pragma unroll
  for (int k = 0; k < 2; k++) {
    int e = tok_i[t * 2 + k];
    int pos = atomicAdd(&cur[e], 1);
    slot_token[pos] = t;
    slot_w[pos] = tok_w[t * 2 + k];
  }
}

// ---------------- pack v3: coalesced stores via wave-local LDS bounce -------
// P chunk [((e*KT+kt)*4+oct)*N + f] (16B) = bf16(W[e][kt*32+oct*8 + 0..7][f])
__device__ __forceinline__ void pack_block(const float* __restrict__ W,
                                           short* __restrict__ P, int K, int N,
                                           int f0, int kt, int e, int tid,
                                           char* smem) {
  const int KT = K >> 5;
  const int lane = tid & 63, w = tid >> 6;
  const float* src = W + (size_t)e * K * N + (size_t)(kt * 32 + w * 8) * N +
                     f0 + lane * 4;
  f32x4 x0 = *(const f32x4*)(src);
  f32x4 x1 = *(const f32x4*)(src + (size_t)N);
  f32x4 x2 = *(const f32x4*)(src + (size_t)2 * N);
  f32x4 x3 = *(const f32x4*)(src + (size_t)3 * N);
  f32x4 x4 = *(const f32x4*)(src + (size_t)4 * N);
  f32x4 x5 = *(const f32x4*)(src + (size_t)5 * N);
  f32x4 x6 = *(const f32x4*)(src + (size_t)6 * N);
  f32x4 x7 = *(const f32x4*)(src + (size_t)7 * N);
  unsigned* Lb = (unsigned*)(smem + w * 4608);   // 256 chunks + 16B/8 pad
#pragma unroll
  for (int j = 0; j < 4; j++) {
    u32x4 c;
    c[0] = cvtpk(x0[j], x1[j]);
    c[1] = cvtpk(x2[j], x3[j]);
    c[2] = cvtpk(x4[j], x5[j]);
    c[3] = cvtpk(x6[j], x7[j]);
    int ch = 4 * lane + j;
    *(u32x4*)(Lb + (ch + (ch >> 3)) * 4) = c;
  }
  asm volatile("s_waitcnt lgkmcnt(0)" ::: "memory");
  SB();
  short* dstb = P + (((size_t)(e * KT + kt) * 4 + w) * N + f0) * 8;
#pragma unroll
  for (int j = 0; j < 4; j++) {
    int ch = j * 64 + lane;   // consecutive lanes -> contiguous 1KB store
    u32x4 c = *(const u32x4*)(Lb + (ch + (ch >> 3)) * 4);
    *(u32x4*)(dstb + (size_t)ch * 8) = c;
  }
}

// ---------------- K3: pack gate+up  UNION  gather ---------------------------
__global__ __launch_bounds__(256, 4) void pack_gu_gather_kernel(
    const float* __restrict__ gw, const float* __restrict__ uw,
    short* __restrict__ Pg, short* __restrict__ Pu,
    const float* __restrict__ x, const int* __restrict__ slot_token,
    short* __restrict__ xg) {
  __shared__ char smem[18432];
  const int bid = blockIdx.x;
  const int tid = threadIdx.x;
  if (bid < 5632) {   // 11 x 32 x 16 pack blocks
    const int f0 = (bid % 11) * 256;
    const int kt = (bid / 11) % 32;
    const int ez = bid / 352;
    pack_block(ez < NE ? gw : uw, ez < NE ? Pg : Pu, HD, FD, f0, kt, ez & 7,
               tid, smem);
  } else {            // 2048 gather blocks
    const int slot = bid - 5632;
    const int tok = slot_token[slot];
    f32x4 v = *(const f32x4*)(x + (size_t)tok * HD + tid * 4);
    u32x2 s;
    s[0] = cvtpk(v[0], v[1]);
    s[1] = cvtpk(v[2], v[3]);
    *(u32x2*)&xg[(size_t)slot * HD + tid * 4] = s;
  }
}

// ---------------- K4: fused gate+up GEMM  UNION  pack down ------------------
// gemm grid-part: gx = bid%352 (= e*44+nt), my = bid/352 (m-tile)

#define G_STAGE(S, T) do {                                           \
    glds16(asrc0 + (T) * 32, &As[S][wid * 512]);                     \
    glds16(asrc1 + (T) * 32, &As[S][2048 + wid * 512]);              \
    glds16(bgsrc + (size_t)(T) * 90112, &Bg[S][wid * 512]);          \
    glds16(busrc + (size_t)(T) * 90112, &Bu[S][wid * 512]);          \
  } while (0)

#define G_COMPUTE(S) do {                                                     \
    _Pragma("unroll")                                                         \
    for (int ks = 0; ks < 2; ks++) {                                          \
      const int oct = ks * 2 + l5;                                            \
      short8 a0, a1, bg, bu;                                                  \
      { int r = wm * 64 + l31, p = r >> 1;                                    \
        a0 = *(const short8*)&As[S][p * 64 +                                  \
              ((((r & 1) << 2) | oct) ^ (p & 7)) * 8]; }                      \
      { int r = wm * 64 + 32 + l31, p = r >> 1;                               \
        a1 = *(const short8*)&As[S][p * 64 +                                  \
              ((((r & 1) << 2) | oct) ^ (p & 7)) * 8]; }                      \
      { int n = wn * 32 + l31, pn = n >> 1;                                   \
        int off = pn * 64 + ((((n & 1) << 2) | oct) ^ (pn & 7)) * 8;          \
        bg = *(const short8*)&Bg[S][off];                                     \
        bu = *(const short8*)&Bu[S][off]; }                                   \
      accG0 = __builtin_amdgcn_mfma_f32_32x32x16_bf16(a0, bg, accG0, 0, 0, 0);\
      accU0 = __builtin_amdgcn_mfma_f32_32x32x16_bf16(a0, bu, accU0, 0, 0, 0);\
      accG1 = __builtin_amdgcn_mfma_f32_32x32x16_bf16(a1, bg, accG1, 0, 0, 0);\
      accU1 = __builtin_amdgcn_mfma_f32_32x32x16_bf16(a1, bu, accU1, 0, 0, 0);\
    }                                                                         \
  } while (0)

#define G_ITER(S, T) do {    \
    G_COMPUTE(S);            \
    BARRIER();               \
    G_STAGE(S, (T) + 3);     \
    WAITV(8);                \
    BARRIER();               \
  } while (0)

__global__ __launch_bounds__(256, 3) void gemm_gu_packd_kernel(
    const short* __restrict__ xg, const short* __restrict__ Pg,
    const short* __restrict__ Pu, const int* __restrict__ bases,
    short* __restrict__ m_out, const float* __restrict__ dw,
    short* __restrict__ Pd, int gemmN) {
  __shared__ char smem[49152];
  const int bid = blockIdx.x;
  const int tid = threadIdx.x;

  if (bid >= gemmN) {   // pack-down blocks: 4 x 88 x 8
    const int pid = bid - gemmN;
    const int f0 = (pid & 3) * 256;
    const int kt = (pid >> 2) % 88;
    const int e = pid / 352;
    pack_block(dw, Pd, FD, HD, f0, kt, e, tid, smem);
    return;
  }

  const int gx = bid % 352;
  const int e = gx / 44, nt = gx - e * 44;
  const int b0 = bases[e];
  const int ne = bases[e + 1] - b0;
  const int row0 = (bid / 352) * 128;
  if (row0 >= ne) return;
  const int n0 = nt * 64;

  short (*As)[4096] = (short(*)[4096])smem;              // 3 x 8 KB
  short (*Bg)[2048] = (short(*)[2048])(smem + 24576);    // 3 x 4 KB
  short (*Bu)[2048] = (short(*)[2048])(smem + 36864);    // 3 x 4 KB

  const int lane = tid & 63, wid = tid >> 6;
  const int l31 = lane & 31, l5 = lane >> 5;
  const int wm = wid >> 1, wn = wid & 1;

  const short *asrc0, *asrc1;
  {
    int i = tid;
    int p = i >> 3, j = i & 7, v = j ^ (p & 7);
    int r = 2 * p + (v >> 2), c = v & 3;
    asrc0 = xg + (size_t)(b0 + imin(row0 + r, ne - 1)) * HD + c * 8;
    i = 256 + tid;
    p = i >> 3; j = i & 7; v = j ^ (p & 7);
    r = 2 * p + (v >> 2); c = v & 3;
    asrc1 = xg + (size_t)(b0 + imin(row0 + r, ne - 1)) * HD + c * 8;
  }
  const short *bgsrc, *busrc;
  {
    int p = tid >> 3, j = tid & 7, v = j ^ (p & 7);
    int r = 2 * p + (v >> 2), c = v & 3;
    size_t off = ((size_t)(e * 32 * 4 + c)) * (FD * 8) + (size_t)(n0 + r) * 8;
    bgsrc = Pg + off;
    busrc = Pu + off;
  }

  f32x16 accG0 = (f32x16)0.f, accG1 = (f32x16)0.f;
  f32x16 accU0 = (f32x16)0.f, accU1 = (f32x16)0.f;

  G_STAGE(0, 0); G_STAGE(1, 1); G_STAGE(2, 2);
  WAITV(8);
  BARRIER();

  for (int t = 0; t < 27; t += 3) {   // NTL = 32
    G_ITER(0, t);
    G_ITER(1, t + 1);
    G_ITER(2, t + 2);
  }
  G_ITER(0, 27);
  G_ITER(1, 28);
  G_COMPUTE(2);            // t=29
  WAITV(4); BARRIER();
  G_COMPUTE(0);            // t=30
  WAITV(0); BARRIER();
  G_COMPUTE(1);            // t=31

#pragma unroll
  for (int q = 0; q < 16; q++) {
    int rb_ = (q & 3) + 8 * (q >> 2) + 4 * l5;
    {
      int r = row0 + wm * 64 + rb_;
      if (r < ne) {
        float g = accG0[q], u = accU0[q];
        float mv = (g / (1.f + __expf(-g))) * u;
        m_out[(size_t)(b0 + r) * FD + n0 + wn * 32 + l31] = f2bf(mv);
      }
    }
    {
      int r = row0 + wm * 64 + 32 + rb_;
      if (r < ne) {
        float g = accG1[q], u = accU1[q];
        float mv = (g / (1.f + __expf(-g))) * u;
        m_out[(size_t)(b0 + r) * FD + n0 + wn * 32 + l31] = f2bf(mv);
      }
    }
  }
}

// ============ down grouped GEMM (BM=64 BN=64 BK=64, all-glds 3-deep) ========

#define D_STAGE(S, T) do {                                           \
    glds16(asrcA0 + (T) * 64, &As[S][wid * 512]);                    \
    glds16(asrcA1 + (T) * 64, &As[S][2048 + wid * 512]);             \
    glds16(bsrc0 + (size_t)(T) * 65536, &Bs[S][wid * 512]);          \
    glds16(bsrc1 + (size_t)(T) * 65536, &Bs[S][2048 + wid * 512]);   \
  } while (0)

#define D_COMPUTE(S) do {                                                     \
    _Pragma("unroll")                                                         \
    for (int ks = 0; ks < 4; ks++) {                                          \
      const int sub = ks >> 1, oct = (ks & 1) * 2 + l5;                       \
      short8 a, b;                                                            \
      { int r = wm * 32 + l31, p = r >> 1;                                    \
        a = *(const short8*)&As[S][sub * 2048 + p * 64 +                      \
              ((((r & 1) << 2) | oct) ^ (p & 7)) * 8]; }                      \
      { int n = wn * 32 + l31, pn = n >> 1;                                   \
        b = *(const short8*)&Bs[S][sub * 2048 + pn * 64 +                     \
              ((((n & 1) << 2) | oct) ^ (pn & 7)) * 8]; }                     \
      acc = __builtin_amdgcn_mfma_f32_32x32x16_bf16(a, b, acc, 0, 0, 0);      \
    }                                                                         \
  } while (0)

#define D_ITER(S, T) do {    \
    D_COMPUTE(S);            \
    BARRIER();               \
    D_STAGE(S, (T) + 3);     \
    WAITV(8);                \
    BARRIER();               \
  } while (0)

__global__ __launch_bounds__(256, 3) void down_kernel(
    const short* __restrict__ m_in, const short* __restrict__ Pd,
    const int* __restrict__ bases, const float* __restrict__ slot_w,
    const int* __restrict__ slot_token, float* __restrict__ out) {
  const int bx = blockIdx.x;
  const int e = bx >> 4, nt = bx & 15;
  const int b0 = bases[e];
  const int ne = bases[e + 1] - b0;
  const int row0 = blockIdx.y * 64;
  if (row0 >= ne) return;
  const int n0 = nt * 64;

  __shared__ short As[3][4096];
  __shared__ short Bs[3][4096];

  const int tid = threadIdx.x;
  const int lane = tid & 63, wid = tid >> 6;
  const int l31 = lane & 31, l5 = lane >> 5;
  const int wm = wid >> 1, wn = wid & 1;

  const short *asrcA0, *asrcA1;
  {
    int p = tid >> 3, j = tid & 7, v = j ^ (p & 7);
    int r = 2 * p + (v >> 2), c = v & 3;
    const short* base = m_in + (size_t)(b0 + imin(row0 + r, ne - 1)) * FD;
    asrcA0 = base + c * 8;
    asrcA1 = base + 32 + c * 8;
  }
  const short *bsrc0, *bsrc1;
  {
    int p = tid >> 3, j = tid & 7, v = j ^ (p & 7);
    int r = 2 * p + (v >> 2), c = v & 3;
    bsrc0 = Pd + ((size_t)((e * 88 + 0) * 4 + c)) * (HD * 8) + (size_t)(n0 + r) * 8;
    bsrc1 = Pd + ((size_t)((e * 88 + 1) * 4 + c)) * (HD * 8) + (size_t)(n0 + r) * 8;
  }

  f32x16 acc = (f32x16)0.f;

  D_STAGE(0, 0); D_STAGE(1, 1); D_STAGE(2, 2);
  WAITV(8);
  BARRIER();

  for (int t = 0; t < 39; t += 3) {   // NTL = 44
    D_ITER(0, t);
    D_ITER(1, t + 1);
    D_ITER(2, t + 2);
  }
  D_ITER(0, 39);
  D_ITER(1, 40);
  D_COMPUTE(2);            // t=41
  WAITV(4); BARRIER();
  D_COMPUTE(0);            // t=42
  WAITV(0); BARRIER();
  D_COMPUTE(1);            // t=43

#pragma unroll
  for (int q = 0; q < 16; q++) {
    int r = row0 + wm * 32 + (q & 3) + 8 * (q >> 2) + 4 * l5;
    if (r < ne) {
      int slot = b0 + r;
      int tok = slot_token[slot];
      atomicAdd(&out[(size_t)tok * HD + n0 + wn * 32 + l31],
                acc[q] * slot_w[slot]);
    }
  }
}

extern "C" void kernel_launch(void* const* d_in, const int* in_sizes, int n_in,
                              void* d_out, int out_size, void* d_ws,
                              size_t ws_size, hipStream_t stream) {
  const float* x = (const float*)d_in[0];
  const float* rw = (const float*)d_in[1];
  const float* gw = (const float*)d_in[2];
  const float* uw = (const float*)d_in[3];
  const float* dw = (const float*)d_in[4];
  float* out = (float*)d_out;

  char* ws = (char*)d_ws;
  int* counts = (int*)(ws + 0);
  int* bases = (int*)(ws + 128);
  int* tok_i = (int*)(ws + 256);
  float* tok_w = (float*)(ws + 8448);
  int* slot_token = (int*)(ws + 16640);
  float* slot_w = (float*)(ws + 24832);
  short* xg = (short*)(ws + 41216);           // 2048 x 1024 bf16     (4.19 MB)
  short* m  = (short*)(ws + 4235520);         // 2048 x 2816 bf16     (11.5 MB)
  short* Pg = (short*)(ws + 15769856);        // gate panels          (46.1 MB)
  short* Pu = (short*)(ws + 61907200);        // up panels            (46.1 MB)
  short* PdBig = (short*)(ws + 108044544);    // down panels          (46.1 MB)
  const bool big = ws_size >= (size_t)108044544 + 46137344;
  short* Pd = big ? PdBig : Pg;   // small-ws: pack down after gemm, into Pg

  (void)hipMemsetAsync(counts, 0, 64, stream);
  (void)hipMemsetAsync(out, 0, (size_t)out_size * 4, stream);
  router_kernel<<<NT, 64, 0, stream>>>(x, rw, counts, tok_i, tok_w);
  scanfill_kernel<<<1, 1024, 0, stream>>>(counts, tok_i, tok_w, bases,
                                          slot_token, slot_w);
  // K3: pack gate+up panels  ∪  gather activations
  pack_gu_gather_kernel<<<7680, 256, 0, stream>>>(gw, uw, Pg, Pu, x,
                                                  slot_token, xg);
  // K4: fused gate/up GEMM (+silu epilogue)  [∪ pack down if ws allows]
  if (big) {
    gemm_gu_packd_kernel<<<5632 + 2816, 256, 0, stream>>>(
        xg, Pg, Pu, bases, m, dw, Pd, 5632);
  } else {
    gemm_gu_packd_kernel<<<5632, 256, 0, stream>>>(xg, Pg, Pu, bases, m, dw,
                                                   Pd, 5632);
    gemm_gu_packd_kernel<<<2816, 256, 0, stream>>>(xg, Pg, Pu, bases, m, dw,
                                                   Pd, 0);
  }
  // K5: down GEMM, atomic combine into out
  down_kernel<<<dim3(128, 32), 256, 0, stream>>>(m, Pd, bases, slot_w,
                                                 slot_token, out);
}